// Round 3
// baseline (12121.288 us; speedup 1.0000x reference)
//
#include <hip/hip_runtime.h>
#include <hip/hip_bf16.h>

// ---------------------------------------------------------------------------
// UnifiedModelRNN: B=256,S=512,I=64,H=256.
// 16-way N-split x 16 batch-groups = 256 blocks (1 per CU, all co-resident).
// Block j of group g owns batch rows [16g,16g+16) x hidden units [16j,16j+16).
// Gate weights (64x320) + ALL head weights are register-resident per block.
// Per step: gates (10 MFMA/wave) -> LSTM (c in regs) -> publish 16x16 h-slice
// (agent-scope stores, parity dbuf in ws) -> release counter -> spin-acquire
// until all 16 slices -> stage full h to LDS -> heads (replicated in every
// block; block j==0 writes pit/time/ar outputs) -> x_{t+1} into LDS.
// One device-scope sync per step; zero weight re-streaming.
// ---------------------------------------------------------------------------

typedef float f32x4 __attribute__((ext_vector_type(4)));
typedef short s16x8 __attribute__((ext_vector_type(8)));

#define S_LEN 512
#define I_DIM 64
#define H_DIM 256
#define K_DIM 320
#define NT    256
#define NGRP  16
#define NSPL  16

// ws element offsets (unsigned short = bf16 storage)
#define WS_WC    0        // Wc: 1024 x 320 row-major, [w_ih | w_hh]
#define WS_PW1   327680   // pit_w1: 64 x 256
#define WS_TW1   344064   // time_w1[:, :256]: 64 x 256
#define WS_ARW1X 360448   // ar_w1[:, 2:66]: 64 x 64
#define WS_ARW2  364544   // ar_w2: 64 x 64
#define WS_WEND  368640
#define WS_HBUF  368640   // u16 elems: [2 parity][16 grp][16 row][256] = 131072
#define WS_CNT_BYTE 999424  // (WS_HBUF+131072)*2 ; u32 cnt[16]

#define OUT_PIT  0
#define OUT_TIME 131072
#define OUT_AR   262144

#define ALD 328   // [x_t|h] LDS row stride (bf16 elems)
#define XLD 72

__device__ __forceinline__ float sigf(float x) {
  return 1.0f / (1.0f + __expf(-x));
}
__device__ __forceinline__ float tanh_fast(float x) {
  float c = fminf(fmaxf(x, -15.0f), 15.0f);
  float e = __expf(2.0f * c);
  return (e - 1.0f) / (e + 1.0f);
}
__device__ __forceinline__ unsigned short f2bf(float f) {
  __hip_bfloat16 h = __float2bfloat16(f);
  return *reinterpret_cast<unsigned short*>(&h);
}

__global__ void prep_kernel(const float* __restrict__ w_ih,
                            const float* __restrict__ w_hh,
                            const float* __restrict__ pit_w1,
                            const float* __restrict__ time_w1,
                            const float* __restrict__ ar_w1,
                            const float* __restrict__ ar_w2,
                            unsigned short* __restrict__ ws) {
  if (blockIdx.x == 0 && threadIdx.x < NGRP) {
    unsigned int* cnt = (unsigned int*)((char*)ws + WS_CNT_BYTE);
    cnt[threadIdx.x] = 0;   // visible to rnn_kernel via kernel-boundary flush
  }
  int idx = blockIdx.x * 256 + threadIdx.x;
  if (idx >= WS_WEND) return;
  float v;
  if (idx < WS_PW1) {
    int r = idx / K_DIM;
    int k = idx - r * K_DIM;
    v = (k < I_DIM) ? w_ih[r * I_DIM + k] : w_hh[r * H_DIM + (k - I_DIM)];
  } else if (idx < WS_TW1) {
    v = pit_w1[idx - WS_PW1];
  } else if (idx < WS_ARW1X) {
    int e = idx - WS_TW1;
    int jj = e >> 8, k = e & 255;
    v = time_w1[jj * 257 + k];
  } else if (idx < WS_ARW2) {
    int e = idx - WS_ARW1X;
    int jj = e >> 6, k = e & 63;
    v = ar_w1[jj * 66 + 2 + k];
  } else {
    v = ar_w2[idx - WS_ARW2];
  }
  ws[idx] = f2bf(v);
}

__global__ __launch_bounds__(NT, 1) void rnn_kernel(
    const float* __restrict__ x,
    const float* __restrict__ b_ih, const float* __restrict__ b_hh,
    const float* __restrict__ pit_b1, const float* __restrict__ pit_w2,
    const float* __restrict__ pit_b2,
    const float* __restrict__ time_w1, const float* __restrict__ time_b1,
    const float* __restrict__ time_w2, const float* __restrict__ time_b2,
    const float* __restrict__ ar_w1, const float* __restrict__ ar_b1,
    const float* __restrict__ ar_b2,
    unsigned short* __restrict__ ws,
    float* __restrict__ out)
{
  __shared__ __align__(16) unsigned short A_lds[16][ALD];    // [x_t(64) | h(256)]
  __shared__ __align__(16) float gLDS[4][16][16];            // gate outputs f32
  __shared__ __align__(16) unsigned short xo_lds[16][XLD];   // x_orig[t]
  __shared__ __align__(16) unsigned short ar1_lds[16][XLD];  // relu(ar1)
  __shared__ float pitp[4][16];
  __shared__ float timep[4][16];

  const int tid  = threadIdx.x;
  const int wave = tid >> 6;     // 0..3 == gate type q == head col-tile
  const int lane = tid & 63;
  const int lrow = lane & 15;
  const int lgrp = lane >> 4;
  // group/split mapping: keep a group's 16 blocks on one XCD (XCD = bid & 7)
  const int bid = blockIdx.x;
  const int mm  = bid >> 3;            // 0..31
  const int j   = mm & 15;             // split index (hidden slice)
  const int g   = (bid & 7) + 8 * (mm >> 4);  // group 0..15
  const int b0  = g * 16;

  unsigned int* hbuf32 = (unsigned int*)(ws + WS_HBUF);  // [2][16][16][128]
  unsigned int* cntg   = (unsigned int*)((char*)ws + WS_CNT_BYTE) + g;

  // ---- register-resident weights ----
  s16x8 wg[10];                        // gate type `wave`, units [16j,16j+16)
  const int grow = wave * 256 + j * 16 + lrow;
#pragma unroll
  for (int kt = 0; kt < 10; ++kt)
    wg[kt] = *reinterpret_cast<const s16x8*>(
        &ws[WS_WC + grow * K_DIM + kt * 32 + 8 * lgrp]);
  const float gbias = b_ih[grow] + b_hh[grow];

  const int hcol = wave * 16 + lrow;   // head col 0..63
  s16x8 pw1[8], tw1[8], arx[2], aw2[2];
#pragma unroll
  for (int kt = 0; kt < 8; ++kt) {
    pw1[kt] = *reinterpret_cast<const s16x8*>(&ws[WS_PW1 + hcol * 256 + kt * 32 + 8 * lgrp]);
    tw1[kt] = *reinterpret_cast<const s16x8*>(&ws[WS_TW1 + hcol * 256 + kt * 32 + 8 * lgrp]);
  }
#pragma unroll
  for (int kt = 0; kt < 2; ++kt) {
    arx[kt] = *reinterpret_cast<const s16x8*>(&ws[WS_ARW1X + hcol * 64 + kt * 32 + 8 * lgrp]);
    aw2[kt] = *reinterpret_cast<const s16x8*>(&ws[WS_ARW2 + hcol * 64 + kt * 32 + 8 * lgrp]);
  }
  const float pb1v = pit_b1[hcol], pw2v = pit_w2[hcol];
  const float tb1v = time_b1[hcol], tw2v = time_w2[hcol];
  const float twlv = time_w1[hcol * 257 + 256];
  const float ab1v = ar_b1[hcol], ab2v = ar_b2[hcol];
  const float arpv = ar_w1[hcol * 66 + 0], artv = ar_w1[hcol * 66 + 1];
  const float pb2 = pit_b2[0], tb2 = time_b2[0];

  // ---- prologue: zero A, stage x0, ar_out[:,0,:] ----
  for (int i = tid; i < 16 * ALD; i += NT) (&A_lds[0][0])[i] = 0;
  const int xr  = tid >> 4;
  const int xc4 = (tid & 15) * 4;
  const size_t xrow = (size_t)(b0 + xr) * S_LEN * I_DIM + xc4;
  {
    float4 xv = *reinterpret_cast<const float4*>(&x[xrow]);
    __syncthreads();
    A_lds[xr][xc4]     = f2bf(xv.x);
    A_lds[xr][xc4 + 1] = f2bf(xv.y);
    A_lds[xr][xc4 + 2] = f2bf(xv.z);
    A_lds[xr][xc4 + 3] = f2bf(xv.w);
    if (j == 0) *reinterpret_cast<float4*>(&out[OUT_AR + xrow]) = xv;
  }
  float cstate[2] = {0.0f, 0.0f};   // threads 0..127: (row tid>>3, units 2*(tid&7)+{0,1})
  __syncthreads();

  // =========================== time loop ===========================
  for (int t = 0; t < S_LEN; ++t) {
    // x_orig[t] load (consumed by ar head later)
    float4 xov = *reinterpret_cast<const float4*>(&x[xrow + (size_t)t * I_DIM]);

    // ---- gates: (16x320)@(320x16) per wave, weights in regs ----
    f32x4 acc;
    acc[0] = acc[1] = acc[2] = acc[3] = gbias;
#pragma unroll
    for (int kt = 0; kt < 10; ++kt) {
      s16x8 af = *reinterpret_cast<const s16x8*>(&A_lds[lrow][kt * 32 + 8 * lgrp]);
      acc = __builtin_amdgcn_mfma_f32_16x16x32_bf16(af, wg[kt], acc, 0, 0, 0);
    }
#pragma unroll
    for (int r = 0; r < 4; ++r) gLDS[wave][lgrp * 4 + r][lrow] = acc[r];
    xo_lds[xr][xc4]     = f2bf(xov.x);
    xo_lds[xr][xc4 + 1] = f2bf(xov.y);
    xo_lds[xr][xc4 + 2] = f2bf(xov.z);
    xo_lds[xr][xc4 + 3] = f2bf(xov.w);
    __syncthreads();

    // ---- LSTM update (threads 0..127), publish h-slice to L2 exchange ----
    if (tid < 128) {
      int r = tid >> 3, p = tid & 7, u0 = 2 * p;
      float hh[2];
#pragma unroll
      for (int uu = 0; uu < 2; ++uu) {
        float ig = sigf(gLDS[0][r][u0 + uu]);
        float fg = sigf(gLDS[1][r][u0 + uu]);
        float gg = tanh_fast(gLDS[2][r][u0 + uu]);
        float og = sigf(gLDS[3][r][u0 + uu]);
        float c  = fg * cstate[uu] + ig * gg;
        cstate[uu] = c;
        hh[uu] = og * tanh_fast(c);
      }
      unsigned int pack = (unsigned int)f2bf(hh[0]) | ((unsigned int)f2bf(hh[1]) << 16);
      __hip_atomic_store(&hbuf32[(((size_t)(t & 1) * NGRP + g) * 16 + r) * 128 + j * 8 + p],
                         pack, __ATOMIC_RELAXED, __HIP_MEMORY_SCOPE_AGENT);
    }
    __threadfence();
    __syncthreads();
    if (tid == 0) {
      __hip_atomic_fetch_add(cntg, 1u, __ATOMIC_RELEASE, __HIP_MEMORY_SCOPE_AGENT);
      const unsigned int tgt = 16u * (unsigned int)(t + 1);
      while (__hip_atomic_load(cntg, __ATOMIC_ACQUIRE, __HIP_MEMORY_SCOPE_AGENT) < tgt)
        __builtin_amdgcn_s_sleep(1);
    }
    __syncthreads();

    // ---- stage full h_t -> A_lds h-region ----
#pragma unroll
    for (int kk = 0; kk < 8; ++kk) {
      int e = tid + NT * kk;  // 0..2047 = [row 16][col32 128]
      unsigned int v = __hip_atomic_load(
          &hbuf32[(((size_t)(t & 1) * NGRP + g) * 16 + (e >> 7)) * 128 + (e & 127)],
          __ATOMIC_RELAXED, __HIP_MEMORY_SCOPE_AGENT);
      *(unsigned int*)((char*)&A_lds[0][0] + (e >> 7) * (ALD * 2) + 128 + (e & 127) * 4) = v;
    }
    __syncthreads();

    // ---- heads (replicated in every block) ----
    s16x8 hf[8];
#pragma unroll
    for (int kt = 0; kt < 8; ++kt)
      hf[kt] = *reinterpret_cast<const s16x8*>(&A_lds[lrow][64 + kt * 32 + 8 * lgrp]);

    // pit
    f32x4 pacc;
    pacc[0] = pacc[1] = pacc[2] = pacc[3] = pb1v;
#pragma unroll
    for (int kt = 0; kt < 8; ++kt)
      pacc = __builtin_amdgcn_mfma_f32_16x16x32_bf16(hf[kt], pw1[kt], pacc, 0, 0, 0);
    {
      float v[4];
#pragma unroll
      for (int r = 0; r < 4; ++r) v[r] = fmaxf(pacc[r], 0.0f) * pw2v;
#pragma unroll
      for (int off = 1; off < 16; off <<= 1)
#pragma unroll
        for (int r = 0; r < 4; ++r) v[r] += __shfl_xor(v[r], off);
      if (lrow == 0) {
#pragma unroll
        for (int r = 0; r < 4; ++r) pitp[wave][lgrp * 4 + r] = v[r];
      }
    }
    __syncthreads();

    // time
    float pv[4];
#pragma unroll
    for (int r = 0; r < 4; ++r) {
      int row = lgrp * 4 + r;
      pv[r] = pitp[0][row] + pitp[1][row] + pitp[2][row] + pitp[3][row] + pb2;
    }
    f32x4 tacc;
    tacc[0] = tacc[1] = tacc[2] = tacc[3] = tb1v;
#pragma unroll
    for (int kt = 0; kt < 8; ++kt)
      tacc = __builtin_amdgcn_mfma_f32_16x16x32_bf16(hf[kt], tw1[kt], tacc, 0, 0, 0);
    {
      float v[4];
#pragma unroll
      for (int r = 0; r < 4; ++r) v[r] = fmaxf(tacc[r] + pv[r] * twlv, 0.0f) * tw2v;
#pragma unroll
      for (int off = 1; off < 16; off <<= 1)
#pragma unroll
        for (int r = 0; r < 4; ++r) v[r] += __shfl_xor(v[r], off);
      if (lrow == 0) {
#pragma unroll
        for (int r = 0; r < 4; ++r) timep[wave][lgrp * 4 + r] = v[r];
      }
    }
    __syncthreads();

    float tv[4];
#pragma unroll
    for (int r = 0; r < 4; ++r) {
      int row = lgrp * 4 + r;
      tv[r] = timep[0][row] + timep[1][row] + timep[2][row] + timep[3][row] + tb2;
    }
    if (j == 0 && wave == 0 && lrow == 0) {
#pragma unroll
      for (int r = 0; r < 4; ++r)
        out[OUT_PIT + (size_t)(b0 + lgrp * 4 + r) * S_LEN + t] = pv[r];
    }
    if (j == 0 && wave == 1 && lrow == 0) {
#pragma unroll
      for (int r = 0; r < 4; ++r)
        out[OUT_TIME + (size_t)(b0 + lgrp * 4 + r) * S_LEN + t] = tv[r];
    }

    if (t < S_LEN - 1) {
      // ar1 = relu([pit,time,x_orig] @ ar_w1^T + b)
      f32x4 aacc;
      aacc[0] = aacc[1] = aacc[2] = aacc[3] = ab1v;
#pragma unroll
      for (int kt = 0; kt < 2; ++kt) {
        s16x8 xf = *reinterpret_cast<const s16x8*>(&xo_lds[lrow][kt * 32 + 8 * lgrp]);
        aacc = __builtin_amdgcn_mfma_f32_16x16x32_bf16(xf, arx[kt], aacc, 0, 0, 0);
      }
#pragma unroll
      for (int r = 0; r < 4; ++r) {
        float a1 = aacc[r] + pv[r] * arpv + tv[r] * artv;
        ar1_lds[lgrp * 4 + r][hcol] = f2bf(fmaxf(a1, 0.0f));
      }
      __syncthreads();
      // ar2 -> nxt = x_{t+1}
      f32x4 nacc;
      nacc[0] = nacc[1] = nacc[2] = nacc[3] = ab2v;
#pragma unroll
      for (int kt = 0; kt < 2; ++kt) {
        s16x8 af = *reinterpret_cast<const s16x8*>(&ar1_lds[lrow][kt * 32 + 8 * lgrp]);
        nacc = __builtin_amdgcn_mfma_f32_16x16x32_bf16(af, aw2[kt], nacc, 0, 0, 0);
      }
#pragma unroll
      for (int r = 0; r < 4; ++r) {
        int row = lgrp * 4 + r;
        A_lds[row][hcol] = f2bf(nacc[r]);
        if (j == 0)
          out[OUT_AR + (size_t)(b0 + row) * S_LEN * I_DIM + (size_t)(t + 1) * I_DIM + hcol] = nacc[r];
      }
    }
    __syncthreads();
  }
}

extern "C" void kernel_launch(void* const* d_in, const int* in_sizes, int n_in,
                              void* d_out, int out_size, void* d_ws, size_t ws_size,
                              hipStream_t stream) {
  const float* x       = (const float*)d_in[0];
  const float* w_ih    = (const float*)d_in[1];
  const float* w_hh    = (const float*)d_in[2];
  const float* b_ih    = (const float*)d_in[3];
  const float* b_hh    = (const float*)d_in[4];
  const float* pit_w1  = (const float*)d_in[5];
  const float* pit_b1  = (const float*)d_in[6];
  const float* pit_w2  = (const float*)d_in[7];
  const float* pit_b2  = (const float*)d_in[8];
  const float* time_w1 = (const float*)d_in[9];
  const float* time_b1 = (const float*)d_in[10];
  const float* time_w2 = (const float*)d_in[11];
  const float* time_b2 = (const float*)d_in[12];
  const float* ar_w1   = (const float*)d_in[13];
  const float* ar_b1   = (const float*)d_in[14];
  const float* ar_w2   = (const float*)d_in[15];
  const float* ar_b2   = (const float*)d_in[16];
  unsigned short* ws   = (unsigned short*)d_ws;
  float* out           = (float*)d_out;

  prep_kernel<<<dim3((WS_WEND + 255) / 256), dim3(256), 0, stream>>>(
      w_ih, w_hh, pit_w1, time_w1, ar_w1, ar_w2, ws);
  rnn_kernel<<<dim3(NGRP * NSPL), dim3(NT), 0, stream>>>(
      x, b_ih, b_hh, pit_b1, pit_w2, pit_b2,
      time_w1, time_b1, time_w2, time_b2,
      ar_w1, ar_b1, ar_b2, ws, out);
}

// Round 4
// 7451.841 us; speedup vs baseline: 1.6266x; 1.6266x over previous
//
#include <hip/hip_runtime.h>
#include <hip/hip_bf16.h>

// ---------------------------------------------------------------------------
// UnifiedModelRNN: B=256,S=512,I=64,H=256. 16 blocks x 512 threads (8 waves),
// 1 block/CU; block g owns batch rows [16g,16g+16) for all t. No grid sync.
// Gate weights Wc (1024x320 bf16) split per wave (wave w owns hidden
// [32w,32w+32) = 80 B-frags): kt{3,4,5} register-resident (96 VGPR),
// kt{9} LDS-resident, kt{0,1,2,6,7,8} streamed from L2 each step via
// FRAGMENT-MAJOR layout (contiguous 1KB/frag -> fully coalesced), spread
// across the head-chain phases for overlap. pit/time head weights LDS-
// resident; ar head weights register-resident (role-split by wave).
// ---------------------------------------------------------------------------

typedef float f32x4 __attribute__((ext_vector_type(4)));
typedef short s16x8 __attribute__((ext_vector_type(8)));

#define S_LEN 512
#define I_DIM 64
#define K_DIM 320
#define NT    512

// ws element offsets (unsigned short = bf16), fragment-major regions
#define WS_GF    0        // gates: 640 frags x 512 elems
#define WS_PF    327680   // pit_w1: 32 frags
#define WS_TF    344064   // time_w1[:, :256]: 32 frags
#define WS_AXF   360448   // ar_w1[:, 2:66]: 8 frags
#define WS_A2F   364544   // ar_w2: 8 frags
#define WS_TOTAL 368640

#define OUT_PIT  0
#define OUT_TIME 131072
#define OUT_AR   262144

#define ALD 328   // [x_t(64) | h(256)] LDS row stride (bf16 elems)
#define XLD 72

__device__ __forceinline__ float sigf(float x) {
  return 1.0f / (1.0f + __expf(-x));
}
__device__ __forceinline__ float tanh_fast(float x) {
  float c = fminf(fmaxf(x, -15.0f), 15.0f);
  float e = __expf(2.0f * c);
  return (e - 1.0f) / (e + 1.0f);
}
__device__ __forceinline__ unsigned short f2bf(float f) {
  __hip_bfloat16 h = __float2bfloat16(f);
  return *reinterpret_cast<unsigned short*>(&h);
}

__global__ void prep_kernel(const float* __restrict__ w_ih,
                            const float* __restrict__ w_hh,
                            const float* __restrict__ pit_w1,
                            const float* __restrict__ time_w1,
                            const float* __restrict__ ar_w1,
                            const float* __restrict__ ar_w2,
                            unsigned short* __restrict__ ws) {
  int idx = blockIdx.x * 256 + threadIdx.x;
  if (idx >= WS_TOTAL) return;
  int lane = (idx >> 3) & 63;
  int e    = idx & 7;
  int lrow = lane & 15, lgrp = lane >> 4;
  float v;
  if (idx < WS_PF) {
    int f = idx >> 9;                 // 0..639
    int w = f / 80, r = f - w * 80;
    int qm = r / 10, kt = r - qm * 10;
    int q = qm >> 1, m = qm & 1;
    int row = q * 256 + w * 32 + m * 16 + lrow;
    int col = kt * 32 + lgrp * 8 + e;
    v = (col < I_DIM) ? w_ih[row * I_DIM + col] : w_hh[row * 256 + col - I_DIM];
  } else if (idx < WS_TF) {
    int f = (idx - WS_PF) >> 9;       // 0..31
    int wv = f >> 3, kt = f & 7;
    v = pit_w1[(wv * 16 + lrow) * 256 + kt * 32 + lgrp * 8 + e];
  } else if (idx < WS_AXF) {
    int f = (idx - WS_TF) >> 9;
    int wv = f >> 3, kt = f & 7;
    v = time_w1[(wv * 16 + lrow) * 257 + kt * 32 + lgrp * 8 + e];
  } else if (idx < WS_A2F) {
    int f = (idx - WS_AXF) >> 9;      // 0..7
    int wv = f >> 1, kt = f & 1;
    v = ar_w1[(wv * 16 + lrow) * 66 + 2 + kt * 32 + lgrp * 8 + e];
  } else {
    int f = (idx - WS_A2F) >> 9;
    int wv = f >> 1, kt = f & 1;
    v = ar_w2[(wv * 16 + lrow) * 64 + kt * 32 + lgrp * 8 + e];
  }
  ws[idx] = f2bf(v);
}

#define AFRAG(kt) (*(const s16x8*)&A_lds[lrow][(kt) * 32 + 8 * lgrp])
#define GFRAG(kt, qm) (*(const s16x8*)&ws[((wave * 80 + (qm) * 10 + (kt)) * 64 + lane) * 8])

__global__ __launch_bounds__(NT, 2) void rnn_kernel(
    const float* __restrict__ x,
    const float* __restrict__ b_ih, const float* __restrict__ b_hh,
    const float* __restrict__ pit_b1, const float* __restrict__ pit_w2,
    const float* __restrict__ pit_b2,
    const float* __restrict__ time_w1, const float* __restrict__ time_b1,
    const float* __restrict__ time_w2, const float* __restrict__ time_b2,
    const float* __restrict__ ar_w1, const float* __restrict__ ar_b1,
    const float* __restrict__ ar_b2,
    const unsigned short* __restrict__ ws,
    float* __restrict__ out)
{
  __shared__ __align__(16) unsigned short A_lds[16][ALD];
  __shared__ __align__(16) unsigned short xo_lds[16][XLD];
  __shared__ __align__(16) unsigned short ar1_lds[16][XLD];
  __shared__ __align__(16) unsigned short g9_lds[64 * 512];   // gate kt9 frags
  __shared__ __align__(16) unsigned short pit_lds[32 * 512];  // pit_w1 frags
  __shared__ __align__(16) unsigned short tim_lds[32 * 512];  // time_w1 frags
  __shared__ float pitp[4][16];
  __shared__ float timep[4][16];

  const int tid  = threadIdx.x;
  const int wave = tid >> 6;
  const int lane = tid & 63;
  const int lrow = lane & 15;
  const int lgrp = lane >> 4;
  const int b0   = blockIdx.x * 16;
  const int hcol = (wave & 3) * 16 + lrow;

  // ---- one-time LDS weight staging (coalesced from frag-major ws) ----
  for (int c = tid; c < 4096; c += NT) {
    int f = c >> 6, lc = c & 63;
    int fws = (f >> 3) * 80 + (f & 7) * 10 + 9;
    *(s16x8*)&g9_lds[c * 8] = *(const s16x8*)&ws[(fws * 64 + lc) * 8];
  }
  for (int c = tid; c < 2048; c += NT) {
    *(s16x8*)&pit_lds[c * 8] = *(const s16x8*)&ws[WS_PF + c * 8];
    *(s16x8*)&tim_lds[c * 8] = *(const s16x8*)&ws[WS_TF + c * 8];
  }
  for (int i = tid; i < 16 * ALD; i += NT) (&A_lds[0][0])[i] = 0;

  // ---- register-resident weights ----
  s16x8 wreg[8][3];  // gate kts 3,4,5
#pragma unroll
  for (int qm = 0; qm < 8; ++qm)
#pragma unroll
    for (int jj = 0; jj < 3; ++jj)
      wreg[qm][jj] = GFRAG(3 + jj, qm);

  float gbias[8];
#pragma unroll
  for (int qm = 0; qm < 8; ++qm) {
    int g = (qm >> 1) * 256 + wave * 32 + (qm & 1) * 16 + lrow;
    gbias[qm] = b_ih[g] + b_hh[g];
  }

  s16x8 arw[2];
  float pb1v = 0, pw2v = 0, tb1v = 0, tw2v = 0, twlv = 0;
  float ab1v = 0, arpv = 0, artv = 0, ab2v = 0;
  if (wave < 4) {
    arw[0] = *(const s16x8*)&ws[WS_AXF + (((wave & 3) * 2 + 0) * 64 + lane) * 8];
    arw[1] = *(const s16x8*)&ws[WS_AXF + (((wave & 3) * 2 + 1) * 64 + lane) * 8];
    pb1v = pit_b1[hcol]; pw2v = pit_w2[hcol];
    ab1v = ar_b1[hcol];  arpv = ar_w1[hcol * 66]; artv = ar_w1[hcol * 66 + 1];
  } else {
    arw[0] = *(const s16x8*)&ws[WS_A2F + (((wave & 3) * 2 + 0) * 64 + lane) * 8];
    arw[1] = *(const s16x8*)&ws[WS_A2F + (((wave & 3) * 2 + 1) * 64 + lane) * 8];
    tb1v = time_b1[hcol]; tw2v = time_w2[hcol];
    twlv = time_w1[hcol * 257 + 256]; ab2v = ar_b2[hcol];
  }
  const float pb2 = pit_b2[0], tb2 = time_b2[0];

  // ---- stage x[:,0,:], write ar_out[:,0,:] ----
  const int srow = tid >> 5;
  const int sc2  = (tid & 31) * 2;
  const size_t xbase = (size_t)(b0 + srow) * S_LEN * I_DIM + sc2;
  float2 xpre = *reinterpret_cast<const float2*>(&x[xbase]);
  __syncthreads();
  A_lds[srow][sc2]     = f2bf(xpre.x);
  A_lds[srow][sc2 + 1] = f2bf(xpre.y);
  *reinterpret_cast<float2*>(&out[OUT_AR + xbase]) = xpre;

  float cst[2][4];
#pragma unroll
  for (int m = 0; m < 2; ++m)
#pragma unroll
    for (int r = 0; r < 4; ++r) cst[m][r] = 0.0f;
  __syncthreads();

  // ---- prologue: full gates(0) ----
  f32x4 acc2[8];
#pragma unroll
  for (int qm = 0; qm < 8; ++qm) {
    f32x4 tv; tv[0] = tv[1] = tv[2] = tv[3] = gbias[qm];
    acc2[qm] = tv;
  }
#pragma unroll
  for (int kt = 0; kt < 10; ++kt) {
    s16x8 aK = AFRAG(kt);
#pragma unroll
    for (int qm = 0; qm < 8; ++qm)
      acc2[qm] = __builtin_amdgcn_mfma_f32_16x16x32_bf16(aK, GFRAG(kt, qm), acc2[qm], 0, 0, 0);
  }

  // =========================== time loop ===========================
  for (int t = 0; t < S_LEN; ++t) {
    // stage x_orig[t]; prefetch x[t+1]
    xo_lds[srow][sc2]     = f2bf(xpre.x);
    xo_lds[srow][sc2 + 1] = f2bf(xpre.y);
    if (t + 1 < S_LEN)
      xpre = *reinterpret_cast<const float2*>(&x[xbase + (size_t)(t + 1) * I_DIM]);

    // ---- LSTM (c in regs) -> h into A_lds ----
#pragma unroll
    for (int m = 0; m < 2; ++m)
#pragma unroll
      for (int r = 0; r < 4; ++r) {
        float ig = sigf(acc2[0 + m][r]);
        float fg = sigf(acc2[2 + m][r]);
        float gg = tanh_fast(acc2[4 + m][r]);
        float og = sigf(acc2[6 + m][r]);
        float c  = fg * cst[m][r] + ig * gg;
        cst[m][r] = c;
        A_lds[lgrp * 4 + r][64 + wave * 32 + m * 16 + lrow] = f2bf(og * tanh_fast(c));
      }
#pragma unroll
    for (int qm = 0; qm < 8; ++qm) {
      f32x4 tv; tv[0] = tv[1] = tv[2] = tv[3] = gbias[qm];
      acc2[qm] = tv;
    }
    __syncthreads();  // sync_a: h + xo ready

    // ======== P1: stream kt2, heads main, REG kts, stream kt6, LDS kt9 ======
    s16x8 bld2[8];
#pragma unroll
    for (int qm = 0; qm < 8; ++qm) bld2[qm] = GFRAG(2, qm);

    f32x4 hacc;
    {
      float hb = (wave < 4) ? pb1v : tb1v;
      hacc[0] = hacc[1] = hacc[2] = hacc[3] = hb;
      const unsigned short* hbp = (wave < 4) ? pit_lds : tim_lds;
#pragma unroll
      for (int kt = 0; kt < 8; ++kt) {
        s16x8 aH = *(const s16x8*)&A_lds[lrow][64 + kt * 32 + 8 * lgrp];
        s16x8 bH = *(const s16x8*)&hbp[(((wave & 3) * 8 + kt) * 64 + lane) * 8];
        hacc = __builtin_amdgcn_mfma_f32_16x16x32_bf16(aH, bH, hacc, 0, 0, 0);
      }
    }
    {
      s16x8 aK = AFRAG(2);
#pragma unroll
      for (int qm = 0; qm < 8; ++qm)
        acc2[qm] = __builtin_amdgcn_mfma_f32_16x16x32_bf16(aK, bld2[qm], acc2[qm], 0, 0, 0);
    }
    s16x8 bld6[8];
#pragma unroll
    for (int qm = 0; qm < 8; ++qm) bld6[qm] = GFRAG(6, qm);
#pragma unroll
    for (int jj = 0; jj < 3; ++jj) {
      s16x8 aK = AFRAG(3 + jj);
#pragma unroll
      for (int qm = 0; qm < 8; ++qm)
        acc2[qm] = __builtin_amdgcn_mfma_f32_16x16x32_bf16(aK, wreg[qm][jj], acc2[qm], 0, 0, 0);
    }
    {
      s16x8 aK = AFRAG(6);
#pragma unroll
      for (int qm = 0; qm < 8; ++qm)
        acc2[qm] = __builtin_amdgcn_mfma_f32_16x16x32_bf16(aK, bld6[qm], acc2[qm], 0, 0, 0);
    }
    {
      s16x8 aK = AFRAG(9);
#pragma unroll
      for (int qm = 0; qm < 8; ++qm) {
        s16x8 bK = *(const s16x8*)&g9_lds[((wave * 8 + qm) * 64 + lane) * 8];
        acc2[qm] = __builtin_amdgcn_mfma_f32_16x16x32_bf16(aK, bK, acc2[qm], 0, 0, 0);
      }
    }
    if (wave < 4) {  // pit partial reduce
      float v[4];
#pragma unroll
      for (int r = 0; r < 4; ++r) v[r] = fmaxf(hacc[r], 0.0f) * pw2v;
#pragma unroll
      for (int off = 1; off < 16; off <<= 1)
#pragma unroll
        for (int r = 0; r < 4; ++r) v[r] += __shfl_xor(v[r], off);
      if (lrow == 0) {
#pragma unroll
        for (int r = 0; r < 4; ++r) pitp[wave][lgrp * 4 + r] = v[r];
      }
    }
    __syncthreads();  // sync_c: pit partials ready

    // ======== P2: stream kt7; time finish / ar1-x; pit out ========
    s16x8 bld7[8];
#pragma unroll
    for (int qm = 0; qm < 8; ++qm) bld7[qm] = GFRAG(7, qm);

    f32x4 aracc;
    if (wave < 4) {
      aracc[0] = aracc[1] = aracc[2] = aracc[3] = ab1v;
#pragma unroll
      for (int kt = 0; kt < 2; ++kt) {
        s16x8 aX = *(const s16x8*)&xo_lds[lrow][kt * 32 + 8 * lgrp];
        aracc = __builtin_amdgcn_mfma_f32_16x16x32_bf16(aX, arw[kt], aracc, 0, 0, 0);
      }
      if (wave == 0 && lane < 16) {
        float pvs = pitp[0][lane] + pitp[1][lane] + pitp[2][lane] + pitp[3][lane] + pb2;
        out[OUT_PIT + (size_t)(b0 + lane) * S_LEN + t] = pvs;
      }
    } else {
      float v[4];
#pragma unroll
      for (int r = 0; r < 4; ++r) {
        int row = lgrp * 4 + r;
        float pvr = pitp[0][row] + pitp[1][row] + pitp[2][row] + pitp[3][row] + pb2;
        v[r] = fmaxf(hacc[r] + pvr * twlv, 0.0f) * tw2v;
      }
#pragma unroll
      for (int off = 1; off < 16; off <<= 1)
#pragma unroll
        for (int r = 0; r < 4; ++r) v[r] += __shfl_xor(v[r], off);
      if (lrow == 0) {
#pragma unroll
        for (int r = 0; r < 4; ++r) timep[wave & 3][lgrp * 4 + r] = v[r];
      }
    }
    {
      s16x8 aK = AFRAG(7);
#pragma unroll
      for (int qm = 0; qm < 8; ++qm)
        acc2[qm] = __builtin_amdgcn_mfma_f32_16x16x32_bf16(aK, bld7[qm], acc2[qm], 0, 0, 0);
    }
    __syncthreads();  // sync_d: time partials ready

    // ======== P3: stream kt8; ar1 finish; time out ========
    s16x8 bld8[8];
#pragma unroll
    for (int qm = 0; qm < 8; ++qm) bld8[qm] = GFRAG(8, qm);

    if (wave < 4) {
#pragma unroll
      for (int r = 0; r < 4; ++r) {
        int row = lgrp * 4 + r;
        float pvr = pitp[0][row] + pitp[1][row] + pitp[2][row] + pitp[3][row] + pb2;
        float tvr = timep[0][row] + timep[1][row] + timep[2][row] + timep[3][row] + tb2;
        float a1 = aracc[r] + pvr * arpv + tvr * artv;
        ar1_lds[row][hcol] = f2bf(fmaxf(a1, 0.0f));
      }
    } else if (wave == 4 && lane < 16) {
      float tvs = timep[0][lane] + timep[1][lane] + timep[2][lane] + timep[3][lane] + tb2;
      out[OUT_TIME + (size_t)(b0 + lane) * S_LEN + t] = tvs;
    }
    {
      s16x8 aK = AFRAG(8);
#pragma unroll
      for (int qm = 0; qm < 8; ++qm)
        acc2[qm] = __builtin_amdgcn_mfma_f32_16x16x32_bf16(aK, bld8[qm], acc2[qm], 0, 0, 0);
    }
    __syncthreads();  // sync_e: ar1 ready

    // ======== P4: ar2 -> x_{t+1} (waves 4-7) ========
    if (wave >= 4) {
      f32x4 nacc;
      nacc[0] = nacc[1] = nacc[2] = nacc[3] = ab2v;
#pragma unroll
      for (int kt = 0; kt < 2; ++kt) {
        s16x8 aR = *(const s16x8*)&ar1_lds[lrow][kt * 32 + 8 * lgrp];
        nacc = __builtin_amdgcn_mfma_f32_16x16x32_bf16(aR, arw[kt], nacc, 0, 0, 0);
      }
#pragma unroll
      for (int r = 0; r < 4; ++r) {
        int row = lgrp * 4 + r;
        A_lds[row][hcol] = f2bf(nacc[r]);
        if (t < S_LEN - 1)
          out[OUT_AR + (size_t)(b0 + row) * S_LEN * I_DIM + (size_t)(t + 1) * I_DIM + hcol] = nacc[r];
      }
    }
    __syncthreads();  // sync_f: x_{t+1} staged

    // ======== P5: gates-x kt0,kt1 (streamed) ========
    {
      s16x8 bld0[8];
#pragma unroll
      for (int qm = 0; qm < 8; ++qm) bld0[qm] = GFRAG(0, qm);
      s16x8 bld1[8];
#pragma unroll
      for (int qm = 0; qm < 8; ++qm) bld1[qm] = GFRAG(1, qm);
      s16x8 a0 = AFRAG(0);
#pragma unroll
      for (int qm = 0; qm < 8; ++qm)
        acc2[qm] = __builtin_amdgcn_mfma_f32_16x16x32_bf16(a0, bld0[qm], acc2[qm], 0, 0, 0);
      s16x8 a1 = AFRAG(1);
#pragma unroll
      for (int qm = 0; qm < 8; ++qm)
        acc2[qm] = __builtin_amdgcn_mfma_f32_16x16x32_bf16(a1, bld1[qm], acc2[qm], 0, 0, 0);
    }
  }
}

extern "C" void kernel_launch(void* const* d_in, const int* in_sizes, int n_in,
                              void* d_out, int out_size, void* d_ws, size_t ws_size,
                              hipStream_t stream) {
  const float* x       = (const float*)d_in[0];
  const float* w_ih    = (const float*)d_in[1];
  const float* w_hh    = (const float*)d_in[2];
  const float* b_ih    = (const float*)d_in[3];
  const float* b_hh    = (const float*)d_in[4];
  const float* pit_w1  = (const float*)d_in[5];
  const float* pit_b1  = (const float*)d_in[6];
  const float* pit_w2  = (const float*)d_in[7];
  const float* pit_b2  = (const float*)d_in[8];
  const float* time_w1 = (const float*)d_in[9];
  const float* time_b1 = (const float*)d_in[10];
  const float* time_w2 = (const float*)d_in[11];
  const float* time_b2 = (const float*)d_in[12];
  const float* ar_w1   = (const float*)d_in[13];
  const float* ar_b1   = (const float*)d_in[14];
  const float* ar_w2   = (const float*)d_in[15];
  const float* ar_b2   = (const float*)d_in[16];
  unsigned short* ws   = (unsigned short*)d_ws;
  float* out           = (float*)d_out;

  prep_kernel<<<dim3((WS_TOTAL + 255) / 256), dim3(256), 0, stream>>>(
      w_ih, w_hh, pit_w1, time_w1, ar_w1, ar_w2, ws);
  rnn_kernel<<<dim3(16), dim3(NT), 0, stream>>>(
      x, b_ih, b_hh, pit_b1, pit_w2, pit_b2,
      time_w1, time_b1, time_w2, time_b2,
      ar_w1, ar_b1, ar_b2, ws, out);
}